// Round 5
// baseline (310.867 us; speedup 1.0000x reference)
//
#include <hip/hip_runtime.h>
#include <cstdint>
#include <cstddef>

// Problem constants
#define BB 2
#define TT 2048
#define DMODEL 1024
#define NHEADS 16
#define DK 64

typedef short short8 __attribute__((ext_vector_type(8)));
typedef unsigned short ushort8 __attribute__((ext_vector_type(8)));
typedef float floatx4 __attribute__((ext_vector_type(4)));

// ---------- helpers ----------
__device__ __forceinline__ unsigned short f2bf(float f) {
    uint32_t u = __builtin_bit_cast(uint32_t, f);
    uint32_t r = (u + 0x7FFFu + ((u >> 16) & 1u)) >> 16;
    return (unsigned short)r;
}

#define GLDS16(g, l) __builtin_amdgcn_global_load_lds( \
    (const __attribute__((address_space(1))) void*)(g), \
    (__attribute__((address_space(3))) void*)(l), 16, 0, 0)

// ---------- cast fp32 -> bf16 (vector x4) ----------
__global__ void castk(const float* __restrict__ in, unsigned short* __restrict__ out, int n) {
    int i = (blockIdx.x * blockDim.x + threadIdx.x) * 4;
    if (i >= n) return;
    float4 v = *(const float4*)(in + i);
    ushort4 o;
    o.x = f2bf(v.x); o.y = f2bf(v.y); o.z = f2bf(v.z); o.w = f2bf(v.w);
    *(ushort4*)(out + i) = o;
}

// ---------- bf16 MFMA GEMM, C = A * B^T  (A: [M][K], B: [N][K], C fp32 [M][N]) ----------
// XOR-swizzled LDS staging: row chunk cc stored at slot cc ^ ((row>>1)&3).
__global__ __launch_bounds__(256)
void gemm_bt(const unsigned short* __restrict__ A, const unsigned short* __restrict__ B,
             float* __restrict__ C, int M, int N, int K) {
    __shared__ unsigned short As[128 * 32];
    __shared__ unsigned short Bs[128 * 32];

    const int tid  = threadIdx.x;
    const int lane = tid & 63;
    const int w    = tid >> 6;
    const int wm   = w & 1;
    const int wn   = w >> 1;
    const int quad = lane >> 4;
    const int l16  = lane & 15;

    const int m0 = blockIdx.y * 128;
    const int n0 = blockIdx.x * 128;

    floatx4 acc[4][4];
#pragma unroll
    for (int a = 0; a < 4; a++)
#pragma unroll
        for (int b = 0; b < 4; b++)
            acc[a][b] = (floatx4){0.f, 0.f, 0.f, 0.f};

    const int c0 = w * 128 + lane;
    const int c1 = c0 + 64;
    const int r0 = c0 >> 2, cc0 = (c0 & 3) ^ ((r0 >> 1) & 3);
    const int r1 = c1 >> 2, cc1 = (c1 & 3) ^ ((r1 >> 1) & 3);

    const unsigned short* gA0 = A + (size_t)(m0 + r0) * K + cc0 * 8;
    const unsigned short* gA1 = A + (size_t)(m0 + r1) * K + cc1 * 8;
    const unsigned short* gB0 = B + (size_t)(n0 + r0) * K + cc0 * 8;
    const unsigned short* gB1 = B + (size_t)(n0 + r1) * K + cc1 * 8;

    unsigned short* lA0 = &As[(2 * w + 0) * 512];
    unsigned short* lA1 = &As[(2 * w + 1) * 512];
    unsigned short* lB0 = &Bs[(2 * w + 0) * 512];
    unsigned short* lB1 = &Bs[(2 * w + 1) * 512];

    const int rsw = (l16 >> 1) & 3;   // (row>>1)&3 for all fragment rows this lane reads

    for (int k0 = 0; k0 < K; k0 += 32) {
        __syncthreads();
        GLDS16(gA0 + k0, lA0);
        GLDS16(gA1 + k0, lA1);
        GLDS16(gB0 + k0, lB0);
        GLDS16(gB1 + k0, lB1);
        __syncthreads();

        short8 af[4], bf[4];
#pragma unroll
        for (int t = 0; t < 4; t++) {
            af[t] = *(const short8*)&As[(wm * 64 + t * 16 + l16) * 32 + (quad ^ rsw) * 8];
            bf[t] = *(const short8*)&Bs[(wn * 64 + t * 16 + l16) * 32 + (quad ^ rsw) * 8];
        }
#pragma unroll
        for (int tm = 0; tm < 4; tm++)
#pragma unroll
            for (int tn = 0; tn < 4; tn++)
                acc[tm][tn] = __builtin_amdgcn_mfma_f32_16x16x32_bf16(
                    af[tm], bf[tn], acc[tm][tn], 0, 0, 0);
    }

#pragma unroll
    for (int tm = 0; tm < 4; tm++) {
#pragma unroll
        for (int tn = 0; tn < 4; tn++) {
#pragma unroll
            for (int r = 0; r < 4; r++) {
                int m = m0 + wm * 64 + tm * 16 + quad * 4 + r;
                int n = n0 + wn * 64 + tn * 16 + l16;
                C[(size_t)m * N + n] = acc[tm][tn][r];
            }
        }
    }
}

// ---------- RoPE + split: qkv fp32 [B*T][3072] -> qb,kb bf16 [B*H][T][64] ----------
// q is pre-scaled by 0.125*log2(e) so attention softmax runs in exp2 domain.
__global__ void rope_split(const float* __restrict__ qkv,
                           unsigned short* __restrict__ qb, unsigned short* __restrict__ kb) {
    int idx = blockIdx.x * blockDim.x + threadIdx.x;
    int p = idx & 31;
    int h = (idx >> 5) & 15;
    int t = (idx >> 9) & 2047;
    int b = idx >> 20;

    size_t src = (size_t)(b * TT + t) * 3072 + h * 64 + 2 * p;
    float2 q = *(const float2*)(qkv + src);
    float2 k = *(const float2*)(qkv + src + 1024);

    float invf = __powf(10000.f, -((float)(2 * p)) / 64.f);
    float ang  = (float)t * invf;
    float sn, cs;
    __sincosf(ang, &sn, &cs);

    const float QS = 0.18033688f;   // 0.125 * log2(e)
    size_t dst = ((size_t)(b * NHEADS + h) * TT + t) * 64 + 2 * p;
    ushort2 qo, ko;
    qo.x = f2bf((q.x * cs - q.y * sn) * QS); qo.y = f2bf((q.y * cs + q.x * sn) * QS);
    ko.x = f2bf(k.x * cs - k.y * sn); ko.y = f2bf(k.y * cs + k.x * sn);
    *(ushort2*)(qb + dst) = qo;
    *(ushort2*)(kb + dst) = ko;
}

// ---------- V transpose: qkv fp32 v-slice -> vtb bf16 [B*H][64][T] ----------
__global__ __launch_bounds__(256)
void vtrans(const float* __restrict__ qkv, unsigned short* __restrict__ vtb) {
    __shared__ float tile[64][65];
    const int tid = threadIdx.x;
    const int bh = blockIdx.y;
    const int b = bh >> 4, h = bh & 15;
    const int t0 = blockIdx.x * 64;

    const int row = tid >> 2;
    const float* src = qkv + ((size_t)(b * TT) + t0 + row) * 3072 + 2048 + h * 64;
#pragma unroll
    for (int i = 0; i < 4; i++) {
        int c4 = (tid & 3) * 4 + i;   // 0..15
        float4 v = *(const float4*)(src + c4 * 4);
        tile[row][c4 * 4 + 0] = v.x;
        tile[row][c4 * 4 + 1] = v.y;
        tile[row][c4 * 4 + 2] = v.z;
        tile[row][c4 * 4 + 3] = v.w;
    }
    __syncthreads();

    const int d  = tid >> 2;
    const int tc = tid & 3;
    ushort8 o0, o1;
#pragma unroll
    for (int i = 0; i < 8; i++) o0[i] = f2bf(tile[tc * 16 + i][d]);
#pragma unroll
    for (int i = 0; i < 8; i++) o1[i] = f2bf(tile[tc * 16 + 8 + i][d]);
    unsigned short* dst = vtb + ((size_t)bh * 64 + d) * TT + t0 + tc * 16;
    *(ushort8*)(dst) = o0;
    *(ushort8*)(dst + 8) = o1;
}

// ---------- MFMA flash attention (causal), bf16 in, bf16 out ----------
// Barrier-free: K/V MFMA fragments are loaded directly from global (L2-resident,
// 512 KB per head; blockIdx.x=bh clusters same-head blocks on one XCD's L2).
// Each wave independently owns 16 q-rows; only per-wave LDS for the P C->A transform.
__global__ __launch_bounds__(256, 2)
void attn_mfma(const unsigned short* __restrict__ qb,
               const unsigned short* __restrict__ kb,
               const unsigned short* __restrict__ vtb,
               unsigned short* __restrict__ out) {
    __shared__ unsigned short Ps[64 * 68];    // [qrow][t], stride 68 el = 136 B

    const int tid  = threadIdx.x;
    const int lane = tid & 63;
    const int w    = tid >> 6;
    const int quad = lane >> 4;
    const int l16  = lane & 15;

    const int bh    = blockIdx.x;                    // XCD = linear%8 -> bh-major locality
    const int qtile = gridDim.y - 1 - blockIdx.y;    // longest blocks dispatch first
    const int q0    = qtile * 64;

    const unsigned short* Qp = qb + ((size_t)bh * TT + q0) * 64;
    const unsigned short* Kp = kb + (size_t)bh * TT * 64;
    const unsigned short* Vp = vtb + (size_t)bh * 64 * TT;

    // Q fragments (A-operand: m=l16 wave-local q-row, k=ks*32+quad*8+j)
    short8 aq[2];
#pragma unroll
    for (int ks = 0; ks < 2; ks++)
        aq[ks] = *(const short8*)(Qp + (size_t)(w * 16 + l16) * 64 + ks * 32 + quad * 8);

    floatx4 Oacc[4];
#pragma unroll
    for (int dt = 0; dt < 4; dt++) Oacc[dt] = (floatx4){0.f, 0.f, 0.f, 0.f};
    float mrow[4] = {-1e30f, -1e30f, -1e30f, -1e30f};
    float lrow[4] = {0.f, 0.f, 0.f, 0.f};

    const int ntiles = qtile + 1;
    for (int it = 0; it < ntiles; ++it) {
        const int j0 = it * 64;

        // B-fragments straight from global (no barriers anywhere in this loop).
        short8 kf[2][4], vf[2][4];
#pragma unroll
        for (int ks = 0; ks < 2; ks++)
#pragma unroll
            for (int nt = 0; nt < 4; nt++)
                kf[ks][nt] = *(const short8*)(Kp + (size_t)(j0 + nt * 16 + l16) * 64 + ks * 32 + quad * 8);
#pragma unroll
        for (int ks = 0; ks < 2; ks++)
#pragma unroll
            for (int dt = 0; dt < 4; dt++)
                vf[ks][dt] = *(const short8*)(Vp + (size_t)(dt * 16 + l16) * TT + j0 + ks * 32 + quad * 8);

        // S = Q K^T (wave-local 16x64); Q pre-scaled so S is in exp2 domain
        floatx4 sacc[4];
#pragma unroll
        for (int nt = 0; nt < 4; nt++) sacc[nt] = (floatx4){0.f, 0.f, 0.f, 0.f};
#pragma unroll
        for (int ks = 0; ks < 2; ks++)
#pragma unroll
            for (int nt = 0; nt < 4; nt++)
                sacc[nt] = __builtin_amdgcn_mfma_f32_16x16x32_bf16(aq[ks], kf[ks][nt], sacc[nt], 0, 0, 0);

        // causal mask (only diagonal tile)
        if (it == qtile) {
#pragma unroll
            for (int nt = 0; nt < 4; nt++)
#pragma unroll
                for (int r = 0; r < 4; r++)
                    if (nt * 16 + l16 > w * 16 + quad * 4 + r) sacc[nt][r] = -1e30f;
        }

        // online softmax per q-row in exp2 domain (row = quad*4+r)
        float alpha[4];
#pragma unroll
        for (int r = 0; r < 4; r++) {
            float mx = fmaxf(fmaxf(sacc[0][r], sacc[1][r]), fmaxf(sacc[2][r], sacc[3][r]));
            mx = fmaxf(mx, __shfl_xor(mx, 1));
            mx = fmaxf(mx, __shfl_xor(mx, 2));
            mx = fmaxf(mx, __shfl_xor(mx, 4));
            mx = fmaxf(mx, __shfl_xor(mx, 8));
            float mnew = fmaxf(mrow[r], mx);
            alpha[r] = __builtin_amdgcn_exp2f(mrow[r] - mnew);
            mrow[r] = mnew;
            float psum = 0.f;
#pragma unroll
            for (int nt = 0; nt < 4; nt++) {
                float p = __builtin_amdgcn_exp2f(sacc[nt][r] - mnew);
                sacc[nt][r] = p;
                psum += p;
            }
            psum += __shfl_xor(psum, 1);
            psum += __shfl_xor(psum, 2);
            psum += __shfl_xor(psum, 4);
            psum += __shfl_xor(psum, 8);
            lrow[r] = lrow[r] * alpha[r] + psum;
        }

        // rescale O accumulators
#pragma unroll
        for (int dt = 0; dt < 4; dt++)
#pragma unroll
            for (int r = 0; r < 4; r++) Oacc[dt][r] *= alpha[r];

        // P (C/D layout) -> per-wave LDS -> A-operand layout (no barrier needed)
#pragma unroll
        for (int nt = 0; nt < 4; nt++)
#pragma unroll
            for (int r = 0; r < 4; r++)
                Ps[(w * 16 + quad * 4 + r) * 68 + nt * 16 + l16] = f2bf(sacc[nt][r]);

        short8 ap[2];
#pragma unroll
        for (int ks = 0; ks < 2; ks++) {
            ushort4 lo = *(const ushort4*)&Ps[(w * 16 + l16) * 68 + ks * 32 + quad * 8];
            ushort4 hi = *(const ushort4*)&Ps[(w * 16 + l16) * 68 + ks * 32 + quad * 8 + 4];
            short8 t;
            t[0] = lo.x; t[1] = lo.y; t[2] = lo.z; t[3] = lo.w;
            t[4] = hi.x; t[5] = hi.y; t[6] = hi.z; t[7] = hi.w;
            ap[ks] = t;
        }

        // O += P V  (B-operand: n=d=dt*16+l16, k=t)
#pragma unroll
        for (int ks = 0; ks < 2; ks++)
#pragma unroll
            for (int dt = 0; dt < 4; dt++)
                Oacc[dt] = __builtin_amdgcn_mfma_f32_16x16x32_bf16(ap[ks], vf[ks][dt], Oacc[dt], 0, 0, 0);
    }

    // epilogue: out[b][t][h*64+d] bf16
    const int b = bh >> 4, h = bh & 15;
#pragma unroll
    for (int r = 0; r < 4; r++) {
        float inv = 1.f / lrow[r];
        int t = q0 + w * 16 + quad * 4 + r;
        size_t base = ((size_t)(b * TT + t)) * DMODEL + h * 64;
#pragma unroll
        for (int dt = 0; dt < 4; dt++)
            out[base + dt * 16 + l16] = f2bf(Oacc[dt][r] * inv);
    }
}

// ---------- launch ----------
extern "C" void kernel_launch(void* const* d_in, const int* in_sizes, int n_in,
                              void* d_out, int out_size, void* d_ws, size_t ws_size,
                              hipStream_t stream) {
    const float* x     = (const float*)d_in[0];   // [2,2048,1024]
    const float* w_qkv = (const float*)d_in[1];   // [3072,1024]
    const float* w_out = (const float*)d_in[2];   // [1024,1024]
    float* out = (float*)d_out;                   // [2,2048,1024]

    char* ws = (char*)d_ws;
    const size_t N_X  = (size_t)BB * TT * DMODEL;     // 4,194,304
    const size_t N_WQ = (size_t)3 * DMODEL * DMODEL;  // 3,145,728
    const size_t N_WO = (size_t)DMODEL * DMODEL;      // 1,048,576

    unsigned short* xb   = (unsigned short*)(ws);                 // 8 MB
    unsigned short* wqb  = (unsigned short*)(ws + 8388608);       // 6 MB
    unsigned short* wob  = (unsigned short*)(ws + 14680064);      // 2 MB
    float*          qkv  = (float*)(ws + 16777216);               // 48 MB
    unsigned short* qb   = (unsigned short*)(ws + 67108864);      // 8 MB
    unsigned short* kb   = (unsigned short*)(ws + 75497472);      // 8 MB
    unsigned short* vtb  = (unsigned short*)(ws + 83886080);      // 8 MB
    unsigned short* attb = (unsigned short*)(ws + 92274688);      // 8 MB

    castk<<<N_X  / 1024, 256, 0, stream>>>(x,     xb,  (int)N_X);
    castk<<<N_WQ / 1024, 256, 0, stream>>>(w_qkv, wqb, (int)N_WQ);
    castk<<<N_WO / 1024, 256, 0, stream>>>(w_out, wob, (int)N_WO);

    // qkv = x @ w_qkv^T   (M=4096, N=3072, K=1024)
    gemm_bt<<<dim3(3072 / 128, 4096 / 128), 256, 0, stream>>>(xb, wqb, qkv, 4096, 3072, 1024);

    rope_split<<<(BB * TT * NHEADS * 32) / 256, 256, 0, stream>>>(qkv, qb, kb);
    vtrans<<<dim3(TT / 64, BB * NHEADS), 256, 0, stream>>>(qkv, vtb);

    // grid: x = bh (XCD locality), y = qtile (reversed inside kernel)
    attn_mfma<<<dim3(BB * NHEADS, TT / 64), 256, 0, stream>>>(qb, kb, vtb, attb);

    // out = attn @ w_out^T (M=4096, N=1024, K=1024)
    gemm_bt<<<dim3(1024 / 128, 4096 / 128), 256, 0, stream>>>(attb, wob, out, 4096, 1024, 1024);
}

// Round 6
// 300.602 us; speedup vs baseline: 1.0341x; 1.0341x over previous
//
#include <hip/hip_runtime.h>
#include <cstdint>
#include <cstddef>

// Problem constants
#define BB 2
#define TT 2048
#define DMODEL 1024
#define NHEADS 16
#define DK 64

typedef short short8 __attribute__((ext_vector_type(8)));
typedef unsigned short ushort8 __attribute__((ext_vector_type(8)));
typedef float floatx4 __attribute__((ext_vector_type(4)));

// ---------- helpers ----------
__device__ __forceinline__ unsigned short f2bf(float f) {
    uint32_t u = __builtin_bit_cast(uint32_t, f);
    uint32_t r = (u + 0x7FFFu + ((u >> 16) & 1u)) >> 16;
    return (unsigned short)r;
}

#define GLDS16(g, l) __builtin_amdgcn_global_load_lds( \
    (const __attribute__((address_space(1))) void*)(g), \
    (__attribute__((address_space(3))) void*)(l), 16, 0, 0)

// ---------- cast fp32 -> bf16 (vector x4) ----------
__global__ void castk(const float* __restrict__ in, unsigned short* __restrict__ out, int n) {
    int i = (blockIdx.x * blockDim.x + threadIdx.x) * 4;
    if (i >= n) return;
    float4 v = *(const float4*)(in + i);
    ushort4 o;
    o.x = f2bf(v.x); o.y = f2bf(v.y); o.z = f2bf(v.z); o.w = f2bf(v.w);
    *(ushort4*)(out + i) = o;
}

// ---------- bf16 MFMA GEMM, C = A * B^T  (A: [M][K], B: [N][K], C fp32 [M][N]) ----------
// XOR-swizzled LDS staging: row chunk cc stored at slot cc ^ ((row>>1)&3).
__global__ __launch_bounds__(256)
void gemm_bt(const unsigned short* __restrict__ A, const unsigned short* __restrict__ B,
             float* __restrict__ C, int M, int N, int K) {
    __shared__ unsigned short As[128 * 32];
    __shared__ unsigned short Bs[128 * 32];

    const int tid  = threadIdx.x;
    const int lane = tid & 63;
    const int w    = tid >> 6;
    const int wm   = w & 1;
    const int wn   = w >> 1;
    const int quad = lane >> 4;
    const int l16  = lane & 15;

    const int m0 = blockIdx.y * 128;
    const int n0 = blockIdx.x * 128;

    floatx4 acc[4][4];
#pragma unroll
    for (int a = 0; a < 4; a++)
#pragma unroll
        for (int b = 0; b < 4; b++)
            acc[a][b] = (floatx4){0.f, 0.f, 0.f, 0.f};

    const int c0 = w * 128 + lane;
    const int c1 = c0 + 64;
    const int r0 = c0 >> 2, cc0 = (c0 & 3) ^ ((r0 >> 1) & 3);
    const int r1 = c1 >> 2, cc1 = (c1 & 3) ^ ((r1 >> 1) & 3);

    const unsigned short* gA0 = A + (size_t)(m0 + r0) * K + cc0 * 8;
    const unsigned short* gA1 = A + (size_t)(m0 + r1) * K + cc1 * 8;
    const unsigned short* gB0 = B + (size_t)(n0 + r0) * K + cc0 * 8;
    const unsigned short* gB1 = B + (size_t)(n0 + r1) * K + cc1 * 8;

    unsigned short* lA0 = &As[(2 * w + 0) * 512];
    unsigned short* lA1 = &As[(2 * w + 1) * 512];
    unsigned short* lB0 = &Bs[(2 * w + 0) * 512];
    unsigned short* lB1 = &Bs[(2 * w + 1) * 512];

    const int rsw = (l16 >> 1) & 3;   // (row>>1)&3 for all fragment rows this lane reads

    for (int k0 = 0; k0 < K; k0 += 32) {
        __syncthreads();
        GLDS16(gA0 + k0, lA0);
        GLDS16(gA1 + k0, lA1);
        GLDS16(gB0 + k0, lB0);
        GLDS16(gB1 + k0, lB1);
        __syncthreads();

        short8 af[4], bf[4];
#pragma unroll
        for (int t = 0; t < 4; t++) {
            af[t] = *(const short8*)&As[(wm * 64 + t * 16 + l16) * 32 + (quad ^ rsw) * 8];
            bf[t] = *(const short8*)&Bs[(wn * 64 + t * 16 + l16) * 32 + (quad ^ rsw) * 8];
        }
#pragma unroll
        for (int tm = 0; tm < 4; tm++)
#pragma unroll
            for (int tn = 0; tn < 4; tn++)
                acc[tm][tn] = __builtin_amdgcn_mfma_f32_16x16x32_bf16(
                    af[tm], bf[tn], acc[tm][tn], 0, 0, 0);
    }

#pragma unroll
    for (int tm = 0; tm < 4; tm++) {
#pragma unroll
        for (int tn = 0; tn < 4; tn++) {
#pragma unroll
            for (int r = 0; r < 4; r++) {
                int m = m0 + wm * 64 + tm * 16 + quad * 4 + r;
                int n = n0 + wn * 64 + tn * 16 + l16;
                C[(size_t)m * N + n] = acc[tm][tn][r];
            }
        }
    }
}

// ---------- RoPE + split: qkv fp32 [B*T][3072] -> qb,kb bf16 [B*H][T][64] ----------
// q is pre-scaled by 0.125*log2(e) so attention softmax runs in exp2 domain.
__global__ void rope_split(const float* __restrict__ qkv,
                           unsigned short* __restrict__ qb, unsigned short* __restrict__ kb) {
    int idx = blockIdx.x * blockDim.x + threadIdx.x;
    int p = idx & 31;
    int h = (idx >> 5) & 15;
    int t = (idx >> 9) & 2047;
    int b = idx >> 20;

    size_t src = (size_t)(b * TT + t) * 3072 + h * 64 + 2 * p;
    float2 q = *(const float2*)(qkv + src);
    float2 k = *(const float2*)(qkv + src + 1024);

    float invf = __powf(10000.f, -((float)(2 * p)) / 64.f);
    float ang  = (float)t * invf;
    float sn, cs;
    __sincosf(ang, &sn, &cs);

    const float QS = 0.18033688f;   // 0.125 * log2(e)
    size_t dst = ((size_t)(b * NHEADS + h) * TT + t) * 64 + 2 * p;
    ushort2 qo, ko;
    qo.x = f2bf((q.x * cs - q.y * sn) * QS); qo.y = f2bf((q.y * cs + q.x * sn) * QS);
    ko.x = f2bf(k.x * cs - k.y * sn); ko.y = f2bf(k.y * cs + k.x * sn);
    *(ushort2*)(qb + dst) = qo;
    *(ushort2*)(kb + dst) = ko;
}

// ---------- V transpose: qkv fp32 v-slice -> vtb bf16 [B*H][64][T] ----------
__global__ __launch_bounds__(256)
void vtrans(const float* __restrict__ qkv, unsigned short* __restrict__ vtb) {
    __shared__ float tile[64][65];
    const int tid = threadIdx.x;
    const int bh = blockIdx.y;
    const int b = bh >> 4, h = bh & 15;
    const int t0 = blockIdx.x * 64;

    const int row = tid >> 2;
    const float* src = qkv + ((size_t)(b * TT) + t0 + row) * 3072 + 2048 + h * 64;
#pragma unroll
    for (int i = 0; i < 4; i++) {
        int c4 = (tid & 3) * 4 + i;   // 0..15
        float4 v = *(const float4*)(src + c4 * 4);
        tile[row][c4 * 4 + 0] = v.x;
        tile[row][c4 * 4 + 1] = v.y;
        tile[row][c4 * 4 + 2] = v.z;
        tile[row][c4 * 4 + 3] = v.w;
    }
    __syncthreads();

    const int d  = tid >> 2;
    const int tc = tid & 3;
    ushort8 o0, o1;
#pragma unroll
    for (int i = 0; i < 8; i++) o0[i] = f2bf(tile[tc * 16 + i][d]);
#pragma unroll
    for (int i = 0; i < 8; i++) o1[i] = f2bf(tile[tc * 16 + 8 + i][d]);
    unsigned short* dst = vtb + ((size_t)bh * 64 + d) * TT + t0 + tc * 16;
    *(ushort8*)(dst) = o0;
    *(ushort8*)(dst + 8) = o1;
}

// ---------- MFMA flash attention (causal), barrier-free + register double-buffer ----------
// K/V fragments loaded directly from global (L2-resident; blockIdx.x=bh -> XCD locality).
// Explicit 2-deep register pipeline: prefetch tile i+1 while computing tile i.
struct AttnState {
    floatx4 Oacc[4];
    floatx4* sacc;        // scratch for current tile
    float mrow[4], lrow[4];
};

__global__ __launch_bounds__(256, 2)
void attn_mfma(const unsigned short* __restrict__ qb,
               const unsigned short* __restrict__ kb,
               const unsigned short* __restrict__ vtb,
               unsigned short* __restrict__ out) {
    __shared__ unsigned short Ps[64 * 68];    // [qrow][t], stride 68 el = 136 B

    const int tid  = threadIdx.x;
    const int lane = tid & 63;
    const int w    = tid >> 6;
    const int quad = lane >> 4;
    const int l16  = lane & 15;

    const int bh    = blockIdx.x;                    // XCD = linear%8 -> bh-major locality
    const int qtile = gridDim.y - 1 - blockIdx.y;    // longest blocks dispatch first
    const int q0    = qtile * 64;

    const unsigned short* Qp = qb + ((size_t)bh * TT + q0) * 64;
    const unsigned short* Kp = kb + (size_t)bh * TT * 64;
    const unsigned short* Vp = vtb + (size_t)bh * 64 * TT;

    // Q fragments (A-operand: m=l16 wave-local q-row, k=ks*32+quad*8+j)
    short8 aq[2];
#pragma unroll
    for (int ks = 0; ks < 2; ks++)
        aq[ks] = *(const short8*)(Qp + (size_t)(w * 16 + l16) * 64 + ks * 32 + quad * 8);

    floatx4 Oacc[4];
#pragma unroll
    for (int dt = 0; dt < 4; dt++) Oacc[dt] = (floatx4){0.f, 0.f, 0.f, 0.f};
    float mrow[4] = {-1e30f, -1e30f, -1e30f, -1e30f};
    float lrow[4] = {0.f, 0.f, 0.f, 0.f};

    const int ntiles = qtile + 1;

    // ---- pipeline macros (compile-time buffer names; no runtime indexing) ----
#define LOAD_KV(KF, VF, J0)                                                               \
    {                                                                                     \
        _Pragma("unroll")                                                                 \
        for (int ks = 0; ks < 2; ks++) {                                                  \
            _Pragma("unroll")                                                             \
            for (int nt = 0; nt < 4; nt++)                                                \
                KF[ks][nt] = *(const short8*)(Kp + (size_t)((J0) + nt * 16 + l16) * 64 +  \
                                              ks * 32 + quad * 8);                        \
        }                                                                                 \
        _Pragma("unroll")                                                                 \
        for (int ks = 0; ks < 2; ks++) {                                                  \
            _Pragma("unroll")                                                             \
            for (int dt = 0; dt < 4; dt++)                                                \
                VF[ks][dt] = *(const short8*)(Vp + (size_t)(dt * 16 + l16) * TT + (J0) +  \
                                              ks * 32 + quad * 8);                        \
        }                                                                                 \
    }

#define COMPUTE_TILE(KF, VF, IT)                                                          \
    {                                                                                     \
        floatx4 sacc[4];                                                                  \
        _Pragma("unroll")                                                                 \
        for (int nt = 0; nt < 4; nt++) sacc[nt] = (floatx4){0.f, 0.f, 0.f, 0.f};          \
        _Pragma("unroll")                                                                 \
        for (int ks = 0; ks < 2; ks++) {                                                  \
            _Pragma("unroll")                                                             \
            for (int nt = 0; nt < 4; nt++)                                                \
                sacc[nt] = __builtin_amdgcn_mfma_f32_16x16x32_bf16(aq[ks], KF[ks][nt],    \
                                                                   sacc[nt], 0, 0, 0);    \
        }                                                                                 \
        if ((IT) == qtile) {                                                              \
            _Pragma("unroll")                                                             \
            for (int nt = 0; nt < 4; nt++) {                                              \
                _Pragma("unroll")                                                         \
                for (int r = 0; r < 4; r++)                                               \
                    if (nt * 16 + l16 > w * 16 + quad * 4 + r) sacc[nt][r] = -1e30f;      \
            }                                                                             \
        }                                                                                 \
        float alpha[4];                                                                   \
        _Pragma("unroll")                                                                 \
        for (int r = 0; r < 4; r++) {                                                     \
            float mx = fmaxf(fmaxf(sacc[0][r], sacc[1][r]), fmaxf(sacc[2][r], sacc[3][r]));\
            mx = fmaxf(mx, __shfl_xor(mx, 1));                                            \
            mx = fmaxf(mx, __shfl_xor(mx, 2));                                            \
            mx = fmaxf(mx, __shfl_xor(mx, 4));                                            \
            mx = fmaxf(mx, __shfl_xor(mx, 8));                                            \
            float mnew = fmaxf(mrow[r], mx);                                              \
            alpha[r] = __builtin_amdgcn_exp2f(mrow[r] - mnew);                            \
            mrow[r] = mnew;                                                               \
            float psum = 0.f;                                                             \
            _Pragma("unroll")                                                             \
            for (int nt = 0; nt < 4; nt++) {                                              \
                float p = __builtin_amdgcn_exp2f(sacc[nt][r] - mnew);                     \
                sacc[nt][r] = p;                                                          \
                psum += p;                                                                \
            }                                                                             \
            psum += __shfl_xor(psum, 1);                                                  \
            psum += __shfl_xor(psum, 2);                                                  \
            psum += __shfl_xor(psum, 4);                                                  \
            psum += __shfl_xor(psum, 8);                                                  \
            lrow[r] = lrow[r] * alpha[r] + psum;                                          \
        }                                                                                 \
        _Pragma("unroll")                                                                 \
        for (int dt = 0; dt < 4; dt++) {                                                  \
            _Pragma("unroll")                                                             \
            for (int r = 0; r < 4; r++) Oacc[dt][r] *= alpha[r];                          \
        }                                                                                 \
        _Pragma("unroll")                                                                 \
        for (int nt = 0; nt < 4; nt++) {                                                  \
            _Pragma("unroll")                                                             \
            for (int r = 0; r < 4; r++)                                                   \
                Ps[(w * 16 + quad * 4 + r) * 68 + nt * 16 + l16] = f2bf(sacc[nt][r]);     \
        }                                                                                 \
        short8 ap[2];                                                                     \
        _Pragma("unroll")                                                                 \
        for (int ks = 0; ks < 2; ks++) {                                                  \
            ushort4 lo = *(const ushort4*)&Ps[(w * 16 + l16) * 68 + ks * 32 + quad * 8];  \
            ushort4 hi = *(const ushort4*)&Ps[(w * 16 + l16) * 68 + ks * 32 + quad * 8 + 4];\
            short8 t;                                                                     \
            t[0] = lo.x; t[1] = lo.y; t[2] = lo.z; t[3] = lo.w;                           \
            t[4] = hi.x; t[5] = hi.y; t[6] = hi.z; t[7] = hi.w;                           \
            ap[ks] = t;                                                                   \
        }                                                                                 \
        _Pragma("unroll")                                                                 \
        for (int ks = 0; ks < 2; ks++) {                                                  \
            _Pragma("unroll")                                                             \
            for (int dt = 0; dt < 4; dt++)                                                \
                Oacc[dt] = __builtin_amdgcn_mfma_f32_16x16x32_bf16(ap[ks], VF[ks][dt],    \
                                                                   Oacc[dt], 0, 0, 0);    \
        }                                                                                 \
    }

    short8 kfA[2][4], vfA[2][4], kfB[2][4], vfB[2][4];
    LOAD_KV(kfA, vfA, 0);

    for (int it = 0; it < ntiles; it += 2) {
        if (it + 1 < ntiles) LOAD_KV(kfB, vfB, (it + 1) * 64);
        COMPUTE_TILE(kfA, vfA, it);
        if (it + 1 >= ntiles) break;
        if (it + 2 < ntiles) LOAD_KV(kfA, vfA, (it + 2) * 64);
        COMPUTE_TILE(kfB, vfB, it + 1);
    }
#undef LOAD_KV
#undef COMPUTE_TILE

    // epilogue: out[b][t][h*64+d] bf16
    const int b = bh >> 4, h = bh & 15;
#pragma unroll
    for (int r = 0; r < 4; r++) {
        float inv = 1.f / lrow[r];
        int t = q0 + w * 16 + quad * 4 + r;
        size_t base = ((size_t)(b * TT + t)) * DMODEL + h * 64;
#pragma unroll
        for (int dt = 0; dt < 4; dt++)
            out[base + dt * 16 + l16] = f2bf(Oacc[dt][r] * inv);
    }
}

// ---------- launch ----------
extern "C" void kernel_launch(void* const* d_in, const int* in_sizes, int n_in,
                              void* d_out, int out_size, void* d_ws, size_t ws_size,
                              hipStream_t stream) {
    const float* x     = (const float*)d_in[0];   // [2,2048,1024]
    const float* w_qkv = (const float*)d_in[1];   // [3072,1024]
    const float* w_out = (const float*)d_in[2];   // [1024,1024]
    float* out = (float*)d_out;                   // [2,2048,1024]

    char* ws = (char*)d_ws;
    const size_t N_X  = (size_t)BB * TT * DMODEL;     // 4,194,304
    const size_t N_WQ = (size_t)3 * DMODEL * DMODEL;  // 3,145,728
    const size_t N_WO = (size_t)DMODEL * DMODEL;      // 1,048,576

    unsigned short* xb   = (unsigned short*)(ws);                 // 8 MB
    unsigned short* wqb  = (unsigned short*)(ws + 8388608);       // 6 MB
    unsigned short* wob  = (unsigned short*)(ws + 14680064);      // 2 MB
    float*          qkv  = (float*)(ws + 16777216);               // 48 MB
    unsigned short* qb   = (unsigned short*)(ws + 67108864);      // 8 MB
    unsigned short* kb   = (unsigned short*)(ws + 75497472);      // 8 MB
    unsigned short* vtb  = (unsigned short*)(ws + 83886080);      // 8 MB
    unsigned short* attb = (unsigned short*)(ws + 92274688);      // 8 MB

    castk<<<N_X  / 1024, 256, 0, stream>>>(x,     xb,  (int)N_X);
    castk<<<N_WQ / 1024, 256, 0, stream>>>(w_qkv, wqb, (int)N_WQ);
    castk<<<N_WO / 1024, 256, 0, stream>>>(w_out, wob, (int)N_WO);

    // qkv = x @ w_qkv^T   (M=4096, N=3072, K=1024)
    gemm_bt<<<dim3(3072 / 128, 4096 / 128), 256, 0, stream>>>(xb, wqb, qkv, 4096, 3072, 1024);

    rope_split<<<(BB * TT * NHEADS * 32) / 256, 256, 0, stream>>>(qkv, qb, kb);
    vtrans<<<dim3(TT / 64, BB * NHEADS), 256, 0, stream>>>(qkv, vtb);

    // grid: x = bh (XCD locality), y = qtile (reversed inside kernel)
    attn_mfma<<<dim3(BB * NHEADS, TT / 64), 256, 0, stream>>>(qb, kb, vtb, attb);

    // out = attn @ w_out^T (M=4096, N=1024, K=1024)
    gemm_bt<<<dim3(1024 / 128, 4096 / 128), 256, 0, stream>>>(attb, wob, out, 4096, 1024, 1024);
}